// Round 4
// baseline (2032.440 us; speedup 1.0000x reference)
//
#include <hip/hip_runtime.h>
#include <hip/hip_bf16.h>

// Sinkhorn object matching, scaling-vector formulation, fp8 iteration,
// PERSISTENT kernel: all 100 iterations in one dispatch.
//   S = Q R^T (4096x4096, D=256), K0 = exp(S_aug/0.1), dustbin row/col = z
//   100x: u = 1/(K0 v); v = 1/(K0^T u);  K = diag(u) K0 diag(v); P interior.
// Block b (256 blocks, 1024 thr) holds rows [16b,16b+16) of A8=fp8(K0) AND of
// T8=fp8(K0^T) in LDS (64KB+64KB). 128KB LDS forces 1 block/CU -> all 256
// blocks co-resident -> custom grid barrier is deadlock-free.
// Cross-block data per half-iteration: the 16KB u or v vector (global, fenced).

#define MROWS 4096
#define NCOLS 4096
#define DDIM 256
#define MP1 4097
#define INV_EPS 10.0f
#define NBLK 256

typedef __attribute__((ext_vector_type(8))) short bf16x8;
typedef __attribute__((ext_vector_type(4))) float f32x4;
typedef __attribute__((ext_vector_type(2))) float f32x2;
typedef __attribute__((ext_vector_type(4))) unsigned short u16x4;

static __device__ __forceinline__ unsigned short f2bf(float f) {
  __hip_bfloat16 h = __float2bfloat16(f);
  union { __hip_bfloat16 h; unsigned short s; } c;
  c.h = h;
  return c.s;
}

// ---------------------------------------------------------------------------
// MFMA bf16 GEMM: 128x128 tile, 4 waves (2x2), wave = 64x64 via 4x4 frags of
// 16x16x32. MODE 0: kv=exp(10S) -> fp8 A8[row][col], fp8 T8[col][row].
// MODE 1: val = u[row]*exp(10S)*v[col] -> fp32 K (stride MP1) and P.
// ---------------------------------------------------------------------------
template <int MODE>
__global__ __launch_bounds__(256) void mfma_gemm_kernel(
    const float* __restrict__ Q, const float* __restrict__ R,
    unsigned char* __restrict__ A8, unsigned char* __restrict__ T8,
    float* __restrict__ Kf, float* __restrict__ P,
    const float* __restrict__ u, const float* __restrict__ v)
{
  __shared__ unsigned short Qs[128][40];
  __shared__ unsigned short Rs[128][40];

  const int tid = threadIdx.x;
  const int lane = tid & 63;
  const int wid = tid >> 6;
  const int wy = wid >> 1;
  const int wx = wid & 1;
  const int rb = blockIdx.y * 128;
  const int cb = blockIdx.x * 128;
  const int lr = tid >> 3;
  const int lf = (tid & 7) * 4;

  f32x4 acc[4][4];
#pragma unroll
  for (int m = 0; m < 4; ++m)
#pragma unroll
    for (int n = 0; n < 4; ++n)
      acc[m][n] = (f32x4){0.f, 0.f, 0.f, 0.f};

  for (int k0 = 0; k0 < DDIM; k0 += 32) {
    float4 qv[4], rv[4];
#pragma unroll
    for (int i = 0; i < 4; ++i) {
      qv[i] = *reinterpret_cast<const float4*>(&Q[(size_t)(rb + lr + 32 * i) * DDIM + k0 + lf]);
      rv[i] = *reinterpret_cast<const float4*>(&R[(size_t)(cb + lr + 32 * i) * DDIM + k0 + lf]);
    }
    __syncthreads();
#pragma unroll
    for (int i = 0; i < 4; ++i) {
      u16x4 qs = {f2bf(qv[i].x), f2bf(qv[i].y), f2bf(qv[i].z), f2bf(qv[i].w)};
      u16x4 rs = {f2bf(rv[i].x), f2bf(rv[i].y), f2bf(rv[i].z), f2bf(rv[i].w)};
      *reinterpret_cast<u16x4*>(&Qs[lr + 32 * i][lf]) = qs;
      *reinterpret_cast<u16x4*>(&Rs[lr + 32 * i][lf]) = rs;
    }
    __syncthreads();

    const int ko = (lane >> 4) * 8;
    const int fr = lane & 15;
    bf16x8 af[4], bg[4];
#pragma unroll
    for (int m = 0; m < 4; ++m)
      af[m] = *reinterpret_cast<const bf16x8*>(&Qs[wy * 64 + m * 16 + fr][ko]);
#pragma unroll
    for (int n = 0; n < 4; ++n)
      bg[n] = *reinterpret_cast<const bf16x8*>(&Rs[wx * 64 + n * 16 + fr][ko]);
#pragma unroll
    for (int m = 0; m < 4; ++m)
#pragma unroll
      for (int n = 0; n < 4; ++n)
        acc[m][n] = __builtin_amdgcn_mfma_f32_16x16x32_bf16(af[m], bg[n], acc[m][n], 0, 0, 0);
  }

  // C/D layout (16x16x32): col = lane&15, row = (lane>>4)*4 + reg.
  const int r0 = (lane >> 4) * 4;
  const int fc = lane & 15;
#pragma unroll
  for (int m = 0; m < 4; ++m) {
    const int row0 = rb + wy * 64 + m * 16 + r0;
    float uu[4];
    if (MODE == 1) {
#pragma unroll
      for (int r = 0; r < 4; ++r) uu[r] = u[row0 + r];
    }
#pragma unroll
    for (int n = 0; n < 4; ++n) {
      const int col = cb + wx * 64 + n * 16 + fc;
      if (MODE == 0) {
        float kv[4];
#pragma unroll
        for (int r = 0; r < 4; ++r) kv[r] = __expf(acc[m][n][r] * INV_EPS);
        int packed = __builtin_amdgcn_cvt_pk_fp8_f32(kv[0], kv[1], 0, false);
        packed = __builtin_amdgcn_cvt_pk_fp8_f32(kv[2], kv[3], packed, true);
        *reinterpret_cast<unsigned int*>(&T8[(size_t)col * NCOLS + row0]) = (unsigned int)packed;
#pragma unroll
        for (int r = 0; r < 4; ++r)
          A8[(size_t)(row0 + r) * NCOLS + col] = (unsigned char)(((unsigned int)packed >> (8 * r)) & 0xffu);
      } else {
        const float vc = v[col];
#pragma unroll
        for (int r = 0; r < 4; ++r) {
          const float kv = __expf(acc[m][n][r] * INV_EPS);
          const float val = uu[r] * kv * vc;
          Kf[(size_t)(row0 + r) * MP1 + col] = val;
          P[(size_t)(row0 + r) * NCOLS + col] = val;
        }
      }
    }
  }
}

// ---------------------------------------------------------------------------
// v = ones (4097); zero barrier state (512 u32).
// ---------------------------------------------------------------------------
__global__ void initv_kernel(float* __restrict__ v, unsigned* __restrict__ bar)
{
  const int i = blockIdx.x * 1024 + threadIdx.x;
  if (i < MP1) v[i] = 1.0f;
  if (i < 512) bar[i] = 0u;
}

// ---------------------------------------------------------------------------
// Final K dustbin row/col.
// ---------------------------------------------------------------------------
__global__ void edgeK_kernel(const float* __restrict__ zp, float* __restrict__ Kf,
                             const float* __restrict__ u, const float* __restrict__ v)
{
  const int i = blockIdx.x * 256 + threadIdx.x;
  if (i >= MP1) return;
  const float E = __expf(zp[0] * INV_EPS);
  Kf[(size_t)i * MP1 + NCOLS] = u[i] * E * v[NCOLS];
  Kf[(size_t)MROWS * MP1 + i] = u[MROWS] * E * v[i];
}

// ---------------------------------------------------------------------------
// Hierarchical grid barrier: 8 group counters (one per XCD, blockIdx&7),
// master counter, generation flag. Thread 0 per block does the protocol;
// agent-scope fences make u/v stores visible across XCDs.
// bar layout: [g*32] group counters (g=0..7), [256] master, [288] gen.
// ---------------------------------------------------------------------------
static __device__ __forceinline__ void grid_barrier(unsigned* bar, int bidx)
{
  __syncthreads();
  if (threadIdx.x == 0) {
    __builtin_amdgcn_fence(__ATOMIC_RELEASE, "agent");   // wbL2: push u/v stores
    unsigned* cg  = bar + ((bidx & 7) << 5);
    unsigned* cm  = bar + 256;
    unsigned* gen = bar + 288;
    const unsigned g = __hip_atomic_load(gen, __ATOMIC_RELAXED, __HIP_MEMORY_SCOPE_AGENT);
    const unsigned a = __hip_atomic_fetch_add(cg, 1u, __ATOMIC_RELAXED, __HIP_MEMORY_SCOPE_AGENT);
    if (a == 31u) {                       // last of my 32-block group
      __hip_atomic_store(cg, 0u, __ATOMIC_RELAXED, __HIP_MEMORY_SCOPE_AGENT);
      const unsigned m = __hip_atomic_fetch_add(cm, 1u, __ATOMIC_RELAXED, __HIP_MEMORY_SCOPE_AGENT);
      if (m == 7u) {                      // last group: release everyone
        __hip_atomic_store(cm, 0u, __ATOMIC_RELAXED, __HIP_MEMORY_SCOPE_AGENT);
        __hip_atomic_store(gen, g + 1u, __ATOMIC_RELEASE, __HIP_MEMORY_SCOPE_AGENT);
      } else {
        while (__hip_atomic_load(gen, __ATOMIC_RELAXED, __HIP_MEMORY_SCOPE_AGENT) == g)
          __builtin_amdgcn_s_sleep(4);
      }
    } else {
      while (__hip_atomic_load(gen, __ATOMIC_RELAXED, __HIP_MEMORY_SCOPE_AGENT) == g)
        __builtin_amdgcn_s_sleep(4);
    }
    __builtin_amdgcn_fence(__ATOMIC_ACQUIRE, "agent");   // invL2: see others' stores
  }
  __syncthreads();
}

// ---------------------------------------------------------------------------
// Persistent Sinkhorn iteration kernel. 256 blocks x 1024 threads.
// Block b holds A8 rows [16b,16b+16) and T8 rows [16b,16b+16) in LDS.
// halfpass(lds, x, out): out[16b+r] = 1/(sum_c lds[r][c]*x[c] + E*x[4096]),
// block 0 additionally: out[4096] = 1/(E * sum_{j<=4096} x[j]).
// Wave w owns column strip [256w,256w+256): lane handles 4 cols x 16 rows.
// ---------------------------------------------------------------------------
__global__ __launch_bounds__(1024) void sinkhorn_persist_kernel(
    const unsigned char* __restrict__ A8, const unsigned char* __restrict__ T8,
    float* __restrict__ u, float* __restrict__ v,
    const float* __restrict__ zp, unsigned* __restrict__ bar)
{
  __shared__ unsigned char lA[16 * 4096];
  __shared__ unsigned char lT[16 * 4096];
  __shared__ float scratch[16][4][16];
  __shared__ float dscr[64];

  const int tid = threadIdx.x;
  const int b = blockIdx.x;
  const int lane = tid & 63;
  const int w = tid >> 6;
  const float E = __expf(zp[0] * INV_EPS);

  // one-time: stage this block's A and T row-slices into LDS (64KB each)
  {
    const uint4* gA = reinterpret_cast<const uint4*>(A8 + (size_t)b * 16 * 4096);
    const uint4* gT = reinterpret_cast<const uint4*>(T8 + (size_t)b * 16 * 4096);
    uint4* sA = reinterpret_cast<uint4*>(lA);
    uint4* sT = reinterpret_cast<uint4*>(lT);
#pragma unroll
    for (int i = 0; i < 4; ++i) {
      sA[tid + 1024 * i] = gA[tid + 1024 * i];
      sT[tid + 1024 * i] = gT[tid + 1024 * i];
    }
  }
  __syncthreads();

  const int c0 = (w << 8) + (lane << 2);   // this lane's 4-col strip base

#define HALFPASS(LDS, XVEC, OUT)                                               \
  {                                                                            \
    const float4 xv = *reinterpret_cast<const float4*>((XVEC) + c0);           \
    const float xd = (XVEC)[4096];                                             \
    float acc[16];                                                             \
    _Pragma("unroll")                                                          \
    for (int r = 0; r < 16; ++r) {                                             \
      const unsigned int aw =                                                  \
          *reinterpret_cast<const unsigned int*>((LDS) + r * 4096 + c0);       \
      const f32x2 lo = __builtin_amdgcn_cvt_pk_f32_fp8((int)aw, false);        \
      const f32x2 hi = __builtin_amdgcn_cvt_pk_f32_fp8((int)aw, true);         \
      acc[r] = lo.x * xv.x + lo.y * xv.y + hi.x * xv.z + hi.y * xv.w;          \
    }                                                                          \
    _Pragma("unroll")                                                          \
    for (int r = 0; r < 16; ++r) {                                             \
      acc[r] += __shfl_xor(acc[r], 1, 64);                                     \
      acc[r] += __shfl_xor(acc[r], 2, 64);                                     \
      acc[r] += __shfl_xor(acc[r], 4, 64);                                     \
      acc[r] += __shfl_xor(acc[r], 8, 64);                                     \
    }                                                                          \
    if ((lane & 15) == 0) {                                                    \
      _Pragma("unroll")                                                        \
      for (int r = 0; r < 16; ++r) scratch[w][lane >> 4][r] = acc[r];          \
    }                                                                          \
    if (b == 0) {                                                              \
      float sv = xv.x + xv.y + xv.z + xv.w;                                    \
      sv += __shfl_xor(sv, 1, 64);                                             \
      sv += __shfl_xor(sv, 2, 64);                                             \
      sv += __shfl_xor(sv, 4, 64);                                             \
      sv += __shfl_xor(sv, 8, 64);                                             \
      if ((lane & 15) == 0) dscr[(w << 2) | (lane >> 4)] = sv;                 \
    }                                                                          \
    __syncthreads();                                                           \
    if (w == 0) {                                                              \
      const int rr = lane & 15, q = lane >> 4;                                 \
      float s = 0.f;                                                           \
      _Pragma("unroll")                                                        \
      for (int ww = 0; ww < 16; ++ww) s += scratch[ww][q][rr];                 \
      s += __shfl_xor(s, 16, 64);                                              \
      s += __shfl_xor(s, 32, 64);                                              \
      if (lane < 16) (OUT)[b * 16 + lane] = 1.0f / (s + E * xd);               \
      if (b == 0) {                                                            \
        float t = dscr[lane];                                                  \
        t += __shfl_xor(t, 1, 64);                                             \
        t += __shfl_xor(t, 2, 64);                                             \
        t += __shfl_xor(t, 4, 64);                                             \
        t += __shfl_xor(t, 8, 64);                                             \
        t += __shfl_xor(t, 16, 64);                                            \
        t += __shfl_xor(t, 32, 64);                                            \
        if (lane == 0) (OUT)[4096] = 1.0f / (E * (t + xd));                    \
      }                                                                        \
    }                                                                          \
  }

  for (int it = 0; it < 100; ++it) {
    HALFPASS(lA, v, u);          // u = 1/(K0 v)
    grid_barrier(bar, b);
    HALFPASS(lT, u, v);          // v = 1/(K0^T u)
    grid_barrier(bar, b);
  }
#undef HALFPASS
}

extern "C" void kernel_launch(void* const* d_in, const int* in_sizes, int n_in,
                              void* d_out, int out_size, void* d_ws, size_t ws_size,
                              hipStream_t stream) {
  const float* Q = (const float*)d_in[0];
  const float* R = (const float*)d_in[1];
  const float* z = (const float*)d_in[2];

  float* P = (float*)d_out;
  float* Kf = P + (size_t)MROWS * NCOLS;   // K-region of d_out

  unsigned char* A8 = (unsigned char*)d_ws;                   // 16.8 MB
  unsigned char* T8 = A8 + (size_t)MROWS * NCOLS;             // 16.8 MB
  float* u = (float*)(T8 + (size_t)MROWS * NCOLS);            // 4104 f
  float* v = u + 4104;                                        // 4104 f
  unsigned* bar = (unsigned*)(v + 4104);                      // 512 u32

  mfma_gemm_kernel<0><<<dim3(32, 32), 256, 0, stream>>>(Q, R, A8, T8, nullptr, nullptr, nullptr, nullptr);
  initv_kernel<<<5, 1024, 0, stream>>>(v, bar);
  sinkhorn_persist_kernel<<<NBLK, 1024, 0, stream>>>(A8, T8, u, v, z, bar);
  mfma_gemm_kernel<1><<<dim3(32, 32), 256, 0, stream>>>(Q, R, nullptr, nullptr, Kf, P, u, v);
  edgeK_kernel<<<(MP1 + 255) / 256, 256, 0, stream>>>(z, Kf, u, v);
}

// Round 5
// 872.592 us; speedup vs baseline: 2.3292x; 2.3292x over previous
//
#include <hip/hip_runtime.h>
#include <hip/hip_bf16.h>

// Sinkhorn object matching, scaling-vector formulation, fp8 iteration,
// PERSISTENT kernel with FENCE-FREE grid barriers.
//   S = Q R^T (4096x4096, D=256), K0 = exp(S_aug/0.1), dustbin row/col = z
//   100x: u = 1/(K0 v); v = 1/(K0^T u);  K = diag(u) K0 diag(v); P interior.
// Block b (256 blocks, 1024 thr) holds rows [16b,16b+16) of A8=fp8(K0) AND of
// T8=fp8(K0^T) in LDS. 1 block/CU -> 256 blocks co-resident -> grid barrier ok.
// Cross-block data (u/v, 16KB) moves ONLY through sc0sc1 coherent loads/stores
// (device coherence point), so barriers need no L2 writeback/invalidate.

#define MROWS 4096
#define NCOLS 4096
#define DDIM 256
#define MP1 4097
#define INV_EPS 10.0f
#define NBLK 256

typedef __attribute__((ext_vector_type(8))) short bf16x8;
typedef __attribute__((ext_vector_type(4))) float f32x4;
typedef __attribute__((ext_vector_type(2))) float f32x2;
typedef __attribute__((ext_vector_type(4))) unsigned short u16x4;

static __device__ __forceinline__ unsigned short f2bf(float f) {
  __hip_bfloat16 h = __float2bfloat16(f);
  union { __hip_bfloat16 h; unsigned short s; } c;
  c.h = h;
  return c.s;
}

// Two coherent (L1/L2-bypassing) float4 loads, one waitcnt. The waitcnt lives
// INSIDE the asm so the compiler cannot schedule uses of the results between
// issue and completion (guide rule #18).
static __device__ __forceinline__ void ld2_coherent(const float* p0, const float* p1,
                                                    float4& a, float4& b) {
  asm volatile("global_load_dwordx4 %0, %2, off sc0 sc1\n\t"
               "global_load_dwordx4 %1, %3, off sc0 sc1\n\t"
               "s_waitcnt vmcnt(0)"
               : "=v"(a), "=v"(b)
               : "v"(p0), "v"(p1)
               : "memory");
}
static __device__ __forceinline__ void st_coherent(float* p, float x) {
  asm volatile("global_store_dword %0, %1, off sc0 sc1" :: "v"(p), "v"(x) : "memory");
}

// ---------------------------------------------------------------------------
// MFMA bf16 GEMM: 128x128 tile, 4 waves (2x2), wave = 64x64 via 4x4 frags of
// 16x16x32. MODE 0: kv=exp(10S) -> fp8 A8[row][col], fp8 T8[col][row].
// MODE 1: val = u[row]*exp(10S)*v[col] -> fp32 K (stride MP1) and P.
// ---------------------------------------------------------------------------
template <int MODE>
__global__ __launch_bounds__(256) void mfma_gemm_kernel(
    const float* __restrict__ Q, const float* __restrict__ R,
    unsigned char* __restrict__ A8, unsigned char* __restrict__ T8,
    float* __restrict__ Kf, float* __restrict__ P,
    const float* __restrict__ u, const float* __restrict__ v)
{
  __shared__ unsigned short Qs[128][40];
  __shared__ unsigned short Rs[128][40];

  const int tid = threadIdx.x;
  const int lane = tid & 63;
  const int wid = tid >> 6;
  const int wy = wid >> 1;
  const int wx = wid & 1;
  const int rb = blockIdx.y * 128;
  const int cb = blockIdx.x * 128;
  const int lr = tid >> 3;
  const int lf = (tid & 7) * 4;

  f32x4 acc[4][4];
#pragma unroll
  for (int m = 0; m < 4; ++m)
#pragma unroll
    for (int n = 0; n < 4; ++n)
      acc[m][n] = (f32x4){0.f, 0.f, 0.f, 0.f};

  for (int k0 = 0; k0 < DDIM; k0 += 32) {
    float4 qv[4], rv[4];
#pragma unroll
    for (int i = 0; i < 4; ++i) {
      qv[i] = *reinterpret_cast<const float4*>(&Q[(size_t)(rb + lr + 32 * i) * DDIM + k0 + lf]);
      rv[i] = *reinterpret_cast<const float4*>(&R[(size_t)(cb + lr + 32 * i) * DDIM + k0 + lf]);
    }
    __syncthreads();
#pragma unroll
    for (int i = 0; i < 4; ++i) {
      u16x4 qs = {f2bf(qv[i].x), f2bf(qv[i].y), f2bf(qv[i].z), f2bf(qv[i].w)};
      u16x4 rs = {f2bf(rv[i].x), f2bf(rv[i].y), f2bf(rv[i].z), f2bf(rv[i].w)};
      *reinterpret_cast<u16x4*>(&Qs[lr + 32 * i][lf]) = qs;
      *reinterpret_cast<u16x4*>(&Rs[lr + 32 * i][lf]) = rs;
    }
    __syncthreads();

    const int ko = (lane >> 4) * 8;
    const int fr = lane & 15;
    bf16x8 af[4], bg[4];
#pragma unroll
    for (int m = 0; m < 4; ++m)
      af[m] = *reinterpret_cast<const bf16x8*>(&Qs[wy * 64 + m * 16 + fr][ko]);
#pragma unroll
    for (int n = 0; n < 4; ++n)
      bg[n] = *reinterpret_cast<const bf16x8*>(&Rs[wx * 64 + n * 16 + fr][ko]);
#pragma unroll
    for (int m = 0; m < 4; ++m)
#pragma unroll
      for (int n = 0; n < 4; ++n)
        acc[m][n] = __builtin_amdgcn_mfma_f32_16x16x32_bf16(af[m], bg[n], acc[m][n], 0, 0, 0);
  }

  // C/D layout (16x16x32): col = lane&15, row = (lane>>4)*4 + reg.
  const int r0 = (lane >> 4) * 4;
  const int fc = lane & 15;
#pragma unroll
  for (int m = 0; m < 4; ++m) {
    const int row0 = rb + wy * 64 + m * 16 + r0;
    float uu[4];
    if (MODE == 1) {
#pragma unroll
      for (int r = 0; r < 4; ++r) uu[r] = u[row0 + r];
    }
#pragma unroll
    for (int n = 0; n < 4; ++n) {
      const int col = cb + wx * 64 + n * 16 + fc;
      if (MODE == 0) {
        float kv[4];
#pragma unroll
        for (int r = 0; r < 4; ++r) kv[r] = __expf(acc[m][n][r] * INV_EPS);
        int packed = __builtin_amdgcn_cvt_pk_fp8_f32(kv[0], kv[1], 0, false);
        packed = __builtin_amdgcn_cvt_pk_fp8_f32(kv[2], kv[3], packed, true);
        *reinterpret_cast<unsigned int*>(&T8[(size_t)col * NCOLS + row0]) = (unsigned int)packed;
#pragma unroll
        for (int r = 0; r < 4; ++r)
          A8[(size_t)(row0 + r) * NCOLS + col] = (unsigned char)(((unsigned int)packed >> (8 * r)) & 0xffu);
      } else {
        const float vc = v[col];
#pragma unroll
        for (int r = 0; r < 4; ++r) {
          const float kv = __expf(acc[m][n][r] * INV_EPS);
          const float val = uu[r] * kv * vc;
          Kf[(size_t)(row0 + r) * MP1 + col] = val;
          P[(size_t)(row0 + r) * NCOLS + col] = val;
        }
      }
    }
  }
}

// ---------------------------------------------------------------------------
// v = ones (4097); zero barrier state (512 u32).
// ---------------------------------------------------------------------------
__global__ void initv_kernel(float* __restrict__ v, unsigned* __restrict__ bar)
{
  const int i = blockIdx.x * 1024 + threadIdx.x;
  if (i < MP1) v[i] = 1.0f;
  if (i < 512) bar[i] = 0u;
}

// ---------------------------------------------------------------------------
// Final K dustbin row/col.
// ---------------------------------------------------------------------------
__global__ void edgeK_kernel(const float* __restrict__ zp, float* __restrict__ Kf,
                             const float* __restrict__ u, const float* __restrict__ v)
{
  const int i = blockIdx.x * 256 + threadIdx.x;
  if (i >= MP1) return;
  const float E = __expf(zp[0] * INV_EPS);
  Kf[(size_t)i * MP1 + NCOLS] = u[i] * E * v[NCOLS];
  Kf[(size_t)MROWS * MP1 + i] = u[MROWS] * E * v[i];
}

// ---------------------------------------------------------------------------
// Fence-free hierarchical grid barrier. Relaxed agent-scope atomics only
// (they operate at the device coherence point; u/v data moved via sc0sc1).
// Thread 0's wave issued all of this block's output stores, so its
// s_waitcnt vmcnt(0) guarantees they reached the coherence point first.
// bar: [g*32] group counters (g=0..7), [256] master, [288] generation.
// ---------------------------------------------------------------------------
static __device__ __forceinline__ void grid_barrier(unsigned* bar, int bidx)
{
  if (threadIdx.x == 0) {
    asm volatile("s_waitcnt vmcnt(0)" ::: "memory");
    unsigned* cg  = bar + ((bidx & 7) << 5);
    unsigned* cm  = bar + 256;
    unsigned* gen = bar + 288;
    const unsigned g = __hip_atomic_load(gen, __ATOMIC_RELAXED, __HIP_MEMORY_SCOPE_AGENT);
    const unsigned a = __hip_atomic_fetch_add(cg, 1u, __ATOMIC_RELAXED, __HIP_MEMORY_SCOPE_AGENT);
    if (a == 31u) {                       // last of my 32-block group
      __hip_atomic_store(cg, 0u, __ATOMIC_RELAXED, __HIP_MEMORY_SCOPE_AGENT);
      const unsigned m = __hip_atomic_fetch_add(cm, 1u, __ATOMIC_RELAXED, __HIP_MEMORY_SCOPE_AGENT);
      if (m == 7u) {                      // last group: release everyone
        __hip_atomic_store(cm, 0u, __ATOMIC_RELAXED, __HIP_MEMORY_SCOPE_AGENT);
        __hip_atomic_store(gen, g + 1u, __ATOMIC_RELAXED, __HIP_MEMORY_SCOPE_AGENT);
      } else {
        while (__hip_atomic_load(gen, __ATOMIC_RELAXED, __HIP_MEMORY_SCOPE_AGENT) == g)
          __builtin_amdgcn_s_sleep(1);
      }
    } else {
      while (__hip_atomic_load(gen, __ATOMIC_RELAXED, __HIP_MEMORY_SCOPE_AGENT) == g)
        __builtin_amdgcn_s_sleep(1);
    }
  }
  __syncthreads();
}

// ---------------------------------------------------------------------------
// Persistent Sinkhorn iteration kernel. 256 blocks x 1024 threads.
// Block b holds A8 rows [16b,16b+16) and T8 rows [16b,16b+16) in LDS.
// halfpass(lds, x, out): out[16b+r] = 1/(sum_c lds[r][c]*x[c] + E*x[4096]);
// block 0 additionally: out[4096] = 1/(E * sum_{j<=4096} x[j]).
// Wave w owns cols [256w,256w+256): lane handles 4 cols x 16 rows, then a
// fold-butterfly (17 shfls) reduces 16 regs x 64 lanes -> row rev4(lane&15).
// ---------------------------------------------------------------------------
__global__ __launch_bounds__(1024) void sinkhorn_persist_kernel(
    const unsigned char* __restrict__ A8, const unsigned char* __restrict__ T8,
    float* __restrict__ u, float* __restrict__ v,
    const float* __restrict__ zp, unsigned* __restrict__ bar)
{
  __shared__ unsigned char lA[16 * 4096];
  __shared__ unsigned char lT[16 * 4096];
  __shared__ float scratch[16][17];     // [row][wave], pad 17 -> conflict-free
  __shared__ float dscr[16];

  const int tid = threadIdx.x;
  const int b = blockIdx.x;
  const int lane = tid & 63;
  const int w = tid >> 6;
  const float E = __expf(zp[0] * INV_EPS);
  const int rev4 = ((lane & 1) << 3) | ((lane & 2) << 1) | ((lane & 4) >> 1) | ((lane & 8) >> 3);

  // one-time: stage this block's A and T row-slices into LDS (64KB each)
  {
    const uint4* gA = reinterpret_cast<const uint4*>(A8 + (size_t)b * 16 * 4096);
    const uint4* gT = reinterpret_cast<const uint4*>(T8 + (size_t)b * 16 * 4096);
    uint4* sA = reinterpret_cast<uint4*>(lA);
    uint4* sT = reinterpret_cast<uint4*>(lT);
#pragma unroll
    for (int i = 0; i < 4; ++i) {
      sA[tid + 1024 * i] = gA[tid + 1024 * i];
      sT[tid + 1024 * i] = gT[tid + 1024 * i];
    }
  }
  __syncthreads();

  const int c0 = (w << 8) + (lane << 2);   // this lane's 4-col strip base

#define HALFPASS(LDS, XVEC, OUT)                                               \
  {                                                                            \
    float4 xv, xd4;                                                            \
    ld2_coherent((XVEC) + c0, (XVEC) + 4096, xv, xd4);                         \
    float acc[16];                                                             \
    _Pragma("unroll")                                                          \
    for (int r = 0; r < 16; ++r) {                                             \
      const unsigned int aw =                                                  \
          *reinterpret_cast<const unsigned int*>((LDS) + r * 4096 + c0);       \
      const f32x2 lo = __builtin_amdgcn_cvt_pk_f32_fp8((int)aw, false);        \
      const f32x2 hi = __builtin_amdgcn_cvt_pk_f32_fp8((int)aw, true);         \
      acc[r] = lo.x * xv.x + lo.y * xv.y + hi.x * xv.z + hi.y * xv.w;          \
    }                                                                          \
    float r8[8], r4[4], r2[2], r1;                                             \
    {                                                                          \
      const bool b0 = (lane & 1) != 0;                                         \
      _Pragma("unroll")                                                        \
      for (int k = 0; k < 8; ++k) {                                            \
        const float send = b0 ? acc[k] : acc[k + 8];                           \
        const float keep = b0 ? acc[k + 8] : acc[k];                           \
        r8[k] = keep + __shfl_xor(send, 1, 64);                                \
      }                                                                        \
      const bool b1 = (lane & 2) != 0;                                         \
      _Pragma("unroll")                                                        \
      for (int k = 0; k < 4; ++k) {                                            \
        const float send = b1 ? r8[k] : r8[k + 4];                             \
        const float keep = b1 ? r8[k + 4] : r8[k];                             \
        r4[k] = keep + __shfl_xor(send, 2, 64);                                \
      }                                                                        \
      const bool b2 = (lane & 4) != 0;                                         \
      _Pragma("unroll")                                                        \
      for (int k = 0; k < 2; ++k) {                                            \
        const float send = b2 ? r4[k] : r4[k + 2];                             \
        const float keep = b2 ? r4[k + 2] : r4[k];                             \
        r2[k] = keep + __shfl_xor(send, 4, 64);                                \
      }                                                                        \
      const bool b3 = (lane & 8) != 0;                                         \
      {                                                                        \
        const float send = b3 ? r2[0] : r2[1];                                 \
        const float keep = b3 ? r2[1] : r2[0];                                 \
        r1 = keep + __shfl_xor(send, 8, 64);                                   \
      }                                                                        \
      r1 += __shfl_xor(r1, 16, 64);                                            \
      r1 += __shfl_xor(r1, 32, 64);                                            \
    }                                                                          \
    if (lane < 16) scratch[rev4][w] = r1;                                      \
    if (b == 0) {                                                              \
      float sv = xv.x + xv.y + xv.z + xv.w;                                    \
      sv += __shfl_xor(sv, 1, 64);  sv += __shfl_xor(sv, 2, 64);               \
      sv += __shfl_xor(sv, 4, 64);  sv += __shfl_xor(sv, 8, 64);               \
      sv += __shfl_xor(sv, 16, 64); sv += __shfl_xor(sv, 32, 64);              \
      if (lane == 0) dscr[w] = sv;                                             \
    }                                                                          \
    __syncthreads();                                                           \
    if (w == 0) {                                                              \
      const int rr = lane >> 2, wq = (lane & 3) * 4;                           \
      float s = scratch[rr][wq] + scratch[rr][wq + 1]                          \
              + scratch[rr][wq + 2] + scratch[rr][wq + 3];                     \
      s += __shfl_xor(s, 1, 64);                                               \
      s += __shfl_xor(s, 2, 64);                                               \
      if ((lane & 3) == 0)                                                     \
        st_coherent((OUT) + b * 16 + rr, 1.0f / (s + E * xd4.x));              \
      if (b == 0) {                                                            \
        float t = (lane < 16) ? dscr[lane] : 0.f;                              \
        t += __shfl_xor(t, 1, 64);  t += __shfl_xor(t, 2, 64);                 \
        t += __shfl_xor(t, 4, 64);  t += __shfl_xor(t, 8, 64);                 \
        t += __shfl_xor(t, 16, 64); t += __shfl_xor(t, 32, 64);                \
        if (lane == 0) st_coherent((OUT) + 4096, 1.0f / (E * (t + xd4.x)));    \
      }                                                                        \
    }                                                                          \
  }

  for (int it = 0; it < 100; ++it) {
    HALFPASS(lA, v, u);          // u = 1/(K0 v)
    grid_barrier(bar, b);
    HALFPASS(lT, u, v);          // v = 1/(K0^T u)
    grid_barrier(bar, b);
  }
#undef HALFPASS
}

extern "C" void kernel_launch(void* const* d_in, const int* in_sizes, int n_in,
                              void* d_out, int out_size, void* d_ws, size_t ws_size,
                              hipStream_t stream) {
  const float* Q = (const float*)d_in[0];
  const float* R = (const float*)d_in[1];
  const float* z = (const float*)d_in[2];

  float* P = (float*)d_out;
  float* Kf = P + (size_t)MROWS * NCOLS;   // K-region of d_out

  unsigned char* A8 = (unsigned char*)d_ws;                   // 16.8 MB
  unsigned char* T8 = A8 + (size_t)MROWS * NCOLS;             // 16.8 MB
  float* u = (float*)(T8 + (size_t)MROWS * NCOLS);            // 4104 f
  float* v = u + 4104;                                        // 4104 f
  unsigned* bar = (unsigned*)(v + 4104);                      // 512 u32

  mfma_gemm_kernel<0><<<dim3(32, 32), 256, 0, stream>>>(Q, R, A8, T8, nullptr, nullptr, nullptr, nullptr);
  initv_kernel<<<5, 1024, 0, stream>>>(v, bar);
  sinkhorn_persist_kernel<<<NBLK, 1024, 0, stream>>>(A8, T8, u, v, z, bar);
  mfma_gemm_kernel<1><<<dim3(32, 32), 256, 0, stream>>>(Q, R, nullptr, nullptr, Kf, P, u, v);
  edgeK_kernel<<<(MP1 + 255) / 256, 256, 0, stream>>>(z, Kf, u, v);
}